// Round 2
// baseline (161.575 us; speedup 1.0000x reference)
//
#include <hip/hip_runtime.h>
#include <math.h>

#define NUM_TOKENS 16384
#define NUM_HEADS  32
#define HEAD_SIZE  128
#define TOTAL_PAIRS (NUM_TOKENS * NUM_HEADS)   // 524288
#define NBLOCKS  2048
#define NTHREADS 256

typedef float vfloat4 __attribute__((ext_vector_type(4)));

// Grid-stride merge. Each (token, head) pair (128 floats = 32 float4s) is
// handled by a 16-lane sub-group; each lane processes float4 #sub and
// #(sub+16) of the pair, so per-pair LSE math is computed 16x (not 32x)
// and each thread moves 96B of traffic per iteration.
__global__ __launch_bounds__(NTHREADS) void merge_attn_states_kernel(
    const float* __restrict__ p_out,   // [NUM_TOKENS, NUM_HEADS, HEAD_SIZE]
    const float* __restrict__ p_lse,   // [NUM_HEADS, NUM_TOKENS]
    const float* __restrict__ s_out,   // [NUM_TOKENS, NUM_HEADS, HEAD_SIZE]
    const float* __restrict__ s_lse,   // [NUM_HEADS, NUM_TOKENS]
    float* __restrict__ out,           // [NUM_TOKENS, NUM_HEADS, HEAD_SIZE]
    float* __restrict__ out_lse)       // [NUM_HEADS, NUM_TOKENS]
{
    const int stride = NBLOCKS * NTHREADS;          // 524288 threads
    const int total  = TOTAL_PAIRS * 16;            // 8388608 sub-slices

    const vfloat4* __restrict__ pv = reinterpret_cast<const vfloat4*>(p_out);
    const vfloat4* __restrict__ sv = reinterpret_cast<const vfloat4*>(s_out);
    vfloat4* __restrict__ ov       = reinterpret_cast<vfloat4*>(out);

    for (int idx = blockIdx.x * NTHREADS + threadIdx.x; idx < total; idx += stride) {
        const int pair = idx >> 4;          // (token*32 + head)
        const int sub  = idx & 15;
        const int head  = pair & (NUM_HEADS - 1);
        const int token = pair >> 5;        // log2(NUM_HEADS) = 5
        const int lse_idx = head * NUM_TOKENS + token;

        // Issue the big streaming loads FIRST so they overlap the LSE chain.
        const int f0 = pair * 32 + sub;     // float4 index
        const int f1 = f0 + 16;
        vfloat4 a0 = pv[f0];
        vfloat4 b0 = sv[f0];
        vfloat4 a1 = pv[f1];
        vfloat4 b1 = sv[f1];

        float pl = p_lse[lse_idx];
        float sl = s_lse[lse_idx];
        // +inf -> -inf sanitization (matches vLLM merge_attn_states)
        if (isinf(pl) && pl > 0.0f) pl = -INFINITY;
        if (isinf(sl) && sl > 0.0f) sl = -INFINITY;

        const float m  = fmaxf(pl, sl);
        const float pe = __expf(pl - m);
        const float se = __expf(sl - m);
        const float denom = pe + se;
        const float inv   = __builtin_amdgcn_rcpf(denom);
        const float ps = pe * inv;
        const float ss = se * inv;

        if (sub == 0) {
            out_lse[lse_idx] = __logf(denom) + m;
        }

        vfloat4 r0, r1;
        r0.x = fmaf(a0.x, ps, b0.x * ss);
        r0.y = fmaf(a0.y, ps, b0.y * ss);
        r0.z = fmaf(a0.z, ps, b0.z * ss);
        r0.w = fmaf(a0.w, ps, b0.w * ss);
        r1.x = fmaf(a1.x, ps, b1.x * ss);
        r1.y = fmaf(a1.y, ps, b1.y * ss);
        r1.z = fmaf(a1.z, ps, b1.z * ss);
        r1.w = fmaf(a1.w, ps, b1.w * ss);
        ov[f0] = r0;
        ov[f1] = r1;
    }
}

extern "C" void kernel_launch(void* const* d_in, const int* in_sizes, int n_in,
                              void* d_out, int out_size, void* d_ws, size_t ws_size,
                              hipStream_t stream) {
    const float* p_out = (const float*)d_in[0];  // prefix_output
    const float* p_lse = (const float*)d_in[1];  // prefix_lse
    const float* s_out = (const float*)d_in[2];  // suffix_output
    const float* s_lse = (const float*)d_in[3];  // suffix_lse

    float* out     = (float*)d_out;
    float* out_lse = (float*)d_out + (size_t)NUM_TOKENS * NUM_HEADS * HEAD_SIZE;

    merge_attn_states_kernel<<<NBLOCKS, NTHREADS, 0, stream>>>(
        p_out, p_lse, s_out, s_lse, out, out_lse);
}

// Round 3
// 148.337 us; speedup vs baseline: 1.0892x; 1.0892x over previous
//
#include <hip/hip_runtime.h>
#include <math.h>

#define NUM_TOKENS 16384
#define NUM_HEADS  32
#define HEAD_SIZE  128
#define TOTAL_PAIRS (NUM_TOKENS * NUM_HEADS)          // 524288
#define TOTAL_F4    (TOTAL_PAIRS * (HEAD_SIZE / 4))   // 16777216 float4 slots
#define NTHREADS 256
#define NBLOCKS  32768                                 // threads = 8388608 = TOTAL_F4/2

typedef float vfloat4 __attribute__((ext_vector_type(4)));

// Linear mapping: float4 slot idx -> (pair = idx>>5, sub = idx&31).
// 32 consecutive lanes share one (token, head) pair -> every global load/store
// is a fully contiguous 1KB-per-wave transaction. Each thread handles TWO
// independent slices (idx, idx + TOTAL_F4/2); all global loads are issued
// up-front so 4x16B output loads + 2 LSE pairs are in flight before compute.
__global__ __launch_bounds__(NTHREADS, 8) void merge_attn_states_kernel(
    const float* __restrict__ p_out,   // [NUM_TOKENS, NUM_HEADS, HEAD_SIZE]
    const float* __restrict__ p_lse,   // [NUM_HEADS, NUM_TOKENS]
    const float* __restrict__ s_out,   // [NUM_TOKENS, NUM_HEADS, HEAD_SIZE]
    const float* __restrict__ s_lse,   // [NUM_HEADS, NUM_TOKENS]
    float* __restrict__ out,           // [NUM_TOKENS, NUM_HEADS, HEAD_SIZE]
    float* __restrict__ out_lse)       // [NUM_HEADS, NUM_TOKENS]
{
    const int idx0 = blockIdx.x * NTHREADS + threadIdx.x;
    const int idx1 = idx0 + TOTAL_F4 / 2;

    const vfloat4* __restrict__ pv = reinterpret_cast<const vfloat4*>(p_out);
    const vfloat4* __restrict__ sv = reinterpret_cast<const vfloat4*>(s_out);
    vfloat4* __restrict__ ov       = reinterpret_cast<vfloat4*>(out);

    // --- slice 0 indices ---
    const int pair0 = idx0 >> 5;
    const int sub0  = idx0 & 31;
    const int lse0  = (pair0 & (NUM_HEADS - 1)) * NUM_TOKENS + (pair0 >> 5);
    // --- slice 1 indices ---
    const int pair1 = idx1 >> 5;
    const int sub1  = idx1 & 31;
    const int lse1  = (pair1 & (NUM_HEADS - 1)) * NUM_TOKENS + (pair1 >> 5);

    // Issue ALL global loads before any dependent compute.
    vfloat4 a0 = pv[idx0];
    vfloat4 b0 = sv[idx0];
    vfloat4 a1 = pv[idx1];
    vfloat4 b1 = sv[idx1];
    float pl0 = p_lse[lse0];
    float sl0 = s_lse[lse0];
    float pl1 = p_lse[lse1];
    float sl1 = s_lse[lse1];

    // +inf -> -inf sanitization (matches vLLM merge_attn_states)
    if (isinf(pl0) && pl0 > 0.0f) pl0 = -INFINITY;
    if (isinf(sl0) && sl0 > 0.0f) sl0 = -INFINITY;
    if (isinf(pl1) && pl1 > 0.0f) pl1 = -INFINITY;
    if (isinf(sl1) && sl1 > 0.0f) sl1 = -INFINITY;

    // --- slice 0 scales ---
    const float m0  = fmaxf(pl0, sl0);
    const float pe0 = __expf(pl0 - m0);
    const float se0 = __expf(sl0 - m0);
    const float d0  = pe0 + se0;
    const float i0  = __builtin_amdgcn_rcpf(d0);
    const float ps0 = pe0 * i0;
    const float ss0 = se0 * i0;
    // --- slice 1 scales ---
    const float m1  = fmaxf(pl1, sl1);
    const float pe1 = __expf(pl1 - m1);
    const float se1 = __expf(sl1 - m1);
    const float d1  = pe1 + se1;
    const float i1  = __builtin_amdgcn_rcpf(d1);
    const float ps1 = pe1 * i1;
    const float ss1 = se1 * i1;

    if (sub0 == 0) out_lse[lse0] = __logf(d0) + m0;
    if (sub1 == 0) out_lse[lse1] = __logf(d1) + m1;

    vfloat4 r0, r1;
    r0.x = fmaf(a0.x, ps0, b0.x * ss0);
    r0.y = fmaf(a0.y, ps0, b0.y * ss0);
    r0.z = fmaf(a0.z, ps0, b0.z * ss0);
    r0.w = fmaf(a0.w, ps0, b0.w * ss0);
    r1.x = fmaf(a1.x, ps1, b1.x * ss1);
    r1.y = fmaf(a1.y, ps1, b1.y * ss1);
    r1.z = fmaf(a1.z, ps1, b1.z * ss1);
    r1.w = fmaf(a1.w, ps1, b1.w * ss1);
    ov[idx0] = r0;
    ov[idx1] = r1;
}

extern "C" void kernel_launch(void* const* d_in, const int* in_sizes, int n_in,
                              void* d_out, int out_size, void* d_ws, size_t ws_size,
                              hipStream_t stream) {
    const float* p_out = (const float*)d_in[0];  // prefix_output
    const float* p_lse = (const float*)d_in[1];  // prefix_lse
    const float* s_out = (const float*)d_in[2];  // suffix_output
    const float* s_lse = (const float*)d_in[3];  // suffix_lse

    float* out     = (float*)d_out;
    float* out_lse = (float*)d_out + (size_t)NUM_TOKENS * NUM_HEADS * HEAD_SIZE;

    merge_attn_states_kernel<<<NBLOCKS, NTHREADS, 0, stream>>>(
        p_out, p_lse, s_out, s_lse, out, out_lse);
}

// Round 4
// 145.099 us; speedup vs baseline: 1.1135x; 1.0223x over previous
//
#include <hip/hip_runtime.h>
#include <math.h>

#define NUM_TOKENS 16384
#define NUM_HEADS  32
#define HEAD_SIZE  128
#define TOTAL_PAIRS (NUM_TOKENS * NUM_HEADS)          // 524288
#define TOTAL_F4    (TOTAL_PAIRS * (HEAD_SIZE / 4))   // 16777216 float4 slots
#define NTHREADS 256

typedef float vfloat2 __attribute__((ext_vector_type(2)));
typedef float vfloat4 __attribute__((ext_vector_type(4)));

// ---------------- Kernel 1: LSE merge + scale table ------------------------
// One thread per (head, token) = lse_idx, fully coalesced LSE reads and
// out_lse writes. Scale table written in [pair]=[token*32+head] order
// (scattered 8B stores, write-combined in L2; table is 4MB, L2-resident).
__global__ __launch_bounds__(NTHREADS) void lse_merge_kernel(
    const float* __restrict__ p_lse,   // [NUM_HEADS, NUM_TOKENS]
    const float* __restrict__ s_lse,   // [NUM_HEADS, NUM_TOKENS]
    float* __restrict__ out_lse,       // [NUM_HEADS, NUM_TOKENS]
    vfloat2* __restrict__ scales)      // [TOTAL_PAIRS] (p_scale, s_scale)
{
    const int tid = blockIdx.x * NTHREADS + threadIdx.x;   // = lse_idx
    const int head  = tid >> 14;                           // /NUM_TOKENS
    const int token = tid & (NUM_TOKENS - 1);
    const int pair  = token * NUM_HEADS + head;

    float pl = p_lse[tid];
    float sl = s_lse[tid];
    // +inf -> -inf sanitization (matches vLLM merge_attn_states)
    if (isinf(pl) && pl > 0.0f) pl = -INFINITY;
    if (isinf(sl) && sl > 0.0f) sl = -INFINITY;

    const float m  = fmaxf(pl, sl);
    const float pe = __expf(pl - m);
    const float se = __expf(sl - m);
    const float d  = pe + se;
    const float inv = __builtin_amdgcn_rcpf(d);

    out_lse[tid] = __logf(d) + m;
    vfloat2 sc;
    sc.x = pe * inv;
    sc.y = se * inv;
    scales[pair] = sc;
}

// ---------------- Kernel 2: pure streaming merge ----------------------------
// One float4 slot per thread (round-1 shape: best measured). 32 consecutive
// lanes share a pair -> 1KB contiguous load/store per wave instruction; the
// scale read is one 8B broadcast per 32-lane group from the L2-resident
// table (two adjacent pairs per wave -> a single 64B line).
__global__ __launch_bounds__(NTHREADS) void merge_out_kernel(
    const float* __restrict__ p_out,
    const float* __restrict__ s_out,
    const vfloat2* __restrict__ scales,
    float* __restrict__ out)
{
    const int idx  = blockIdx.x * NTHREADS + threadIdx.x;  // float4 slot
    const int pair = idx >> 5;

    const vfloat4* __restrict__ pv = reinterpret_cast<const vfloat4*>(p_out);
    const vfloat4* __restrict__ sv = reinterpret_cast<const vfloat4*>(s_out);
    vfloat4* __restrict__ ov       = reinterpret_cast<vfloat4*>(out);

    vfloat2 sc = scales[pair];
    vfloat4 a  = pv[idx];
    vfloat4 b  = sv[idx];

    vfloat4 r;
    r.x = fmaf(a.x, sc.x, b.x * sc.y);
    r.y = fmaf(a.y, sc.x, b.y * sc.y);
    r.z = fmaf(a.z, sc.x, b.z * sc.y);
    r.w = fmaf(a.w, sc.x, b.w * sc.y);
    ov[idx] = r;
}

// ---------------- Fallback: round-1 single kernel (if ws too small) --------
__global__ __launch_bounds__(NTHREADS) void merge_fallback_kernel(
    const float* __restrict__ p_out, const float* __restrict__ p_lse,
    const float* __restrict__ s_out, const float* __restrict__ s_lse,
    float* __restrict__ out, float* __restrict__ out_lse)
{
    const int pair = blockIdx.x * 8 + (threadIdx.x >> 5);
    const int lane = threadIdx.x & 31;
    const int lse_idx = (pair & (NUM_HEADS - 1)) * NUM_TOKENS + (pair >> 5);

    float pl = p_lse[lse_idx];
    float sl = s_lse[lse_idx];
    if (isinf(pl) && pl > 0.0f) pl = -INFINITY;
    if (isinf(sl) && sl > 0.0f) sl = -INFINITY;
    const float m  = fmaxf(pl, sl);
    const float pe = __expf(pl - m);
    const float se = __expf(sl - m);
    const float d  = pe + se;
    const float inv = __builtin_amdgcn_rcpf(d);
    const float ps = pe * inv, ss = se * inv;
    if (lane == 0) out_lse[lse_idx] = __logf(d) + m;

    const size_t base = (size_t)pair * HEAD_SIZE;
    const vfloat4* pv = reinterpret_cast<const vfloat4*>(p_out + base);
    const vfloat4* sv = reinterpret_cast<const vfloat4*>(s_out + base);
    vfloat4*       ov = reinterpret_cast<vfloat4*>(out + base);
    vfloat4 a = pv[lane], b = sv[lane], r;
    r.x = fmaf(a.x, ps, b.x * ss);
    r.y = fmaf(a.y, ps, b.y * ss);
    r.z = fmaf(a.z, ps, b.z * ss);
    r.w = fmaf(a.w, ps, b.w * ss);
    ov[lane] = r;
}

extern "C" void kernel_launch(void* const* d_in, const int* in_sizes, int n_in,
                              void* d_out, int out_size, void* d_ws, size_t ws_size,
                              hipStream_t stream) {
    const float* p_out = (const float*)d_in[0];  // prefix_output
    const float* p_lse = (const float*)d_in[1];  // prefix_lse
    const float* s_out = (const float*)d_in[2];  // suffix_output
    const float* s_lse = (const float*)d_in[3];  // suffix_lse

    float* out     = (float*)d_out;
    float* out_lse = (float*)d_out + (size_t)NUM_TOKENS * NUM_HEADS * HEAD_SIZE;

    const size_t scales_bytes = (size_t)TOTAL_PAIRS * sizeof(vfloat2);  // 4 MB

    if (ws_size >= scales_bytes) {
        vfloat2* scales = (vfloat2*)d_ws;
        lse_merge_kernel<<<TOTAL_PAIRS / NTHREADS, NTHREADS, 0, stream>>>(
            p_lse, s_lse, out_lse, scales);
        merge_out_kernel<<<TOTAL_F4 / NTHREADS, NTHREADS, 0, stream>>>(
            p_out, s_out, scales, out);
    } else {
        merge_fallback_kernel<<<TOTAL_PAIRS / 8, NTHREADS, 0, stream>>>(
            p_out, p_lse, s_out, s_lse, out, out_lse);
    }
}